// Round 13
// baseline (280.928 us; speedup 1.0000x reference)
//
#include <hip/hip_runtime.h>
#include <hip/hip_cooperative_groups.h>
#include <hip/hip_bf16.h>
#include <math.h>

namespace cg = cooperative_groups;

#define B_N 4096
#define D_N 1024
#define K_N 256
#define NSTEP 32

typedef __attribute__((ext_vector_type(8))) short bf16x8;           // 4 VGPR
typedef __attribute__((ext_vector_type(8))) unsigned short u16x8;   // 4 VGPR
typedef __attribute__((ext_vector_type(4))) float f32x4;            // MFMA C/D

static constexpr float K_EPS = 1e-8f;

static __device__ __forceinline__ unsigned short f32_to_bf16_rne(float f) {
    unsigned x = __builtin_bit_cast(unsigned, f);
    unsigned r = (x + 0x7FFFu + ((x >> 16) & 1u)) >> 16;
    return (unsigned short)r;
}
static __device__ __forceinline__ float bf16_bits_to_f32(unsigned short h) {
    unsigned x = ((unsigned)h) << 16;
    return __builtin_bit_cast(float, x);
}
// 8 floats -> bf16 hi/lo vectors (fully static, no arrays -> no scratch)
static __device__ __forceinline__ void cvt8(
    float e0, float e1, float e2, float e3,
    float e4, float e5, float e6, float e7, u16x8& hv, u16x8& lv)
{
    ushort h0=f32_to_bf16_rne(e0), h1=f32_to_bf16_rne(e1),
           h2=f32_to_bf16_rne(e2), h3=f32_to_bf16_rne(e3),
           h4=f32_to_bf16_rne(e4), h5=f32_to_bf16_rne(e5),
           h6=f32_to_bf16_rne(e6), h7=f32_to_bf16_rne(e7);
    hv = (u16x8){h0,h1,h2,h3,h4,h5,h6,h7};
    lv = (u16x8){f32_to_bf16_rne(e0 - bf16_bits_to_f32(h0)),
                 f32_to_bf16_rne(e1 - bf16_bits_to_f32(h1)),
                 f32_to_bf16_rne(e2 - bf16_bits_to_f32(h2)),
                 f32_to_bf16_rne(e3 - bf16_bits_to_f32(h3)),
                 f32_to_bf16_rne(e4 - bf16_bits_to_f32(h4)),
                 f32_to_bf16_rne(e5 - bf16_bits_to_f32(h5)),
                 f32_to_bf16_rne(e6 - bf16_bits_to_f32(h6)),
                 f32_to_bf16_rne(e7 - bf16_bits_to_f32(h7))};
}

// ---------------------------------------------------------------------------
// ONE cooperative kernel: 256 blocks x 1024 threads (16 waves, 4/SIMD).
//  Phase A : block n packs centroid n (normalize + hi/lo split) into the
//            MFMA-fragment layout phi/plo (R12-verified mapping).
//  Stage 1 : wave w normalizes dp row brow+w (64 lanes, 6 shfl_xor) and
//            writes XOR-swizzled bf16 hi/lo A-tiles in LDS. Independent of
//            phase A -> runs before the first grid sync.
//  sync #1 : phi/plo visible everywhere.
//  Stage 2 : K-loop, per-wave n-tile nt=w: 2 contiguous 1KB packed-B loads
//            per step, depth-4 register rotation, 3 MFMA/step, no barriers.
//  Stage 3 : simsL (aliases A-tile LDS) -> per-wave top-2 butterfly (wave w
//            owns row w) -> sims/idx/top1 writes + cent gathers.
//  sync #2 : widx complete.
//  Phase C : dp_cluster + index_dp rows, 17 rows/block (256*17 = 4352).
// ---------------------------------------------------------------------------
__global__ __launch_bounds__(1024) void kfused_kernel(
    const float* __restrict__ dp, const float* __restrict__ cent,
    ushort* __restrict__ phi, ushort* __restrict__ plo,
    int* __restrict__ widx,
    float* __restrict__ o_sims, float* __restrict__ o_dpidx,
    float* __restrict__ o_clust, float* __restrict__ o_idxdp,
    float* __restrict__ o_dpcent, float* __restrict__ o_hneg,
    float* __restrict__ o_hnidx, float* __restrict__ o_top1)
{
    __shared__ __align__(16) char ldsbuf[65536];
    ushort* AhL   = (ushort*)ldsbuf;             // 32 KB
    ushort* AlL   = (ushort*)(ldsbuf + 32768);   // 32 KB
    float*  simsL = (float*)ldsbuf;              // 16 KB alias (post stage 2)
    __shared__ float redA[4];
    __shared__ float s_invA;

    int tid  = threadIdx.x;
    int lane = tid & 63;
    int w    = tid >> 6;          // wave 0..15
    int lr   = lane & 15;
    int lg   = lane >> 4;
    int bid  = blockIdx.x;
    int brow = bid * 16;

    // ---------- Phase A ----------
    {
        float s = 0.f;
        float4 v = {};
        if (tid < 256) {
            v = reinterpret_cast<const float4*>(cent + (size_t)bid * D_N)[tid];
            s = v.x*v.x + v.y*v.y + v.z*v.z + v.w*v.w;
            #pragma unroll
            for (int o = 32; o > 0; o >>= 1) s += __shfl_down(s, o);
            if ((tid & 63) == 0) redA[tid >> 6] = s;
        }
        __syncthreads();
        if (tid == 0)
            s_invA = 1.0f / fmaxf(sqrtf(redA[0]+redA[1]+redA[2]+redA[3]), K_EPS);
        __syncthreads();
        if (tid < 256) {
            float inv = s_invA;
            float e0 = v.x*inv, e1 = v.y*inv, e2 = v.z*inv, e3 = v.w*inv;
            ushort h0=f32_to_bf16_rne(e0), h1=f32_to_bf16_rne(e1),
                   h2=f32_to_bf16_rne(e2), h3=f32_to_bf16_rne(e3);
            ushort l0=f32_to_bf16_rne(e0-bf16_bits_to_f32(h0)),
                   l1=f32_to_bf16_rne(e1-bf16_bits_to_f32(h1)),
                   l2=f32_to_bf16_rne(e2-bf16_bits_to_f32(h2)),
                   l3=f32_to_bf16_rne(e3-bf16_bits_to_f32(h3));
            int nt = bid >> 4, lrn = bid & 15;
            int k8 = tid >> 1, half = tid & 1;
            int tt = k8 >> 2, lgn = k8 & 3;
            size_t chunk = (size_t)(nt*32 + tt)*64 + (size_t)(lgn*16 + lrn);
            *reinterpret_cast<ushort4*>(phi + chunk*8 + half*4) =
                make_ushort4(h0, h1, h2, h3);
            *reinterpret_cast<ushort4*>(plo + chunk*8 + half*4) =
                make_ushort4(l0, l1, l2, l3);
        }
    }

    // ---------- Stage 1 (independent of phase A) ----------
    {
        const float4* r4 = reinterpret_cast<const float4*>(
            dp + (size_t)(brow + w) * D_N);
        float4 a0 = r4[lane*4+0], a1 = r4[lane*4+1],
               a2 = r4[lane*4+2], a3 = r4[lane*4+3];
        float s = a0.x*a0.x + a0.y*a0.y + a0.z*a0.z + a0.w*a0.w
                + a1.x*a1.x + a1.y*a1.y + a1.z*a1.z + a1.w*a1.w
                + a2.x*a2.x + a2.y*a2.y + a2.z*a2.z + a2.w*a2.w
                + a3.x*a3.x + a3.y*a3.y + a3.z*a3.z + a3.w*a3.w;
        #pragma unroll
        for (int o = 1; o < 64; o <<= 1) s += __shfl_xor(s, o);
        float inv = 1.0f / fmaxf(sqrtf(s), K_EPS);
        u16x8 hv, lv;
        cvt8(a0.x*inv, a0.y*inv, a0.z*inv, a0.w*inv,
             a1.x*inv, a1.y*inv, a1.z*inv, a1.w*inv, hv, lv);
        int slot = (lane*2 + 0) ^ (w & 7);
        *reinterpret_cast<u16x8*>(&AhL[w*1024 + slot*8]) = hv;
        *reinterpret_cast<u16x8*>(&AlL[w*1024 + slot*8]) = lv;
        cvt8(a2.x*inv, a2.y*inv, a2.z*inv, a2.w*inv,
             a3.x*inv, a3.y*inv, a3.z*inv, a3.w*inv, hv, lv);
        slot = (lane*2 + 1) ^ (w & 7);
        *reinterpret_cast<u16x8*>(&AhL[w*1024 + slot*8]) = hv;
        *reinterpret_cast<u16x8*>(&AlL[w*1024 + slot*8]) = lv;
    }
    __syncthreads();
    __threadfence();
    cg::this_grid().sync();

    // ---------- Stage 2: K-loop ----------
    f32x4 acc = {};
    const ushort* bh = phi + (size_t)w * 32 * 512 + (size_t)lane * 8;
    const ushort* bl = plo + (size_t)w * 32 * 512 + (size_t)lane * 8;
    const char* AhC = (const char*)AhL;
    const char* AlC = (const char*)AlL;

    auto step = [&](int t, bf16x8 hb, bf16x8 lb) {
        unsigned ca = (unsigned)((4*t + lg) ^ (lr & 7));
        unsigned ao = (unsigned)lr * 2048u + ca * 16u;
        bf16x8 ah = *reinterpret_cast<const bf16x8*>(AhC + ao);
        bf16x8 al = *reinterpret_cast<const bf16x8*>(AlC + ao);
        acc = __builtin_amdgcn_mfma_f32_16x16x32_bf16(ah, hb, acc, 0, 0, 0);
        acc = __builtin_amdgcn_mfma_f32_16x16x32_bf16(ah, lb, acc, 0, 0, 0);
        acc = __builtin_amdgcn_mfma_f32_16x16x32_bf16(al, hb, acc, 0, 0, 0);
    };
    #define LBF(t, H, L)                                                  \
        H = *reinterpret_cast<const bf16x8*>(bh + (size_t)(t) * 512);     \
        L = *reinterpret_cast<const bf16x8*>(bl + (size_t)(t) * 512);
    bf16x8 h0,l0,h1,l1,h2,l2,h3,l3;
    LBF(0,h0,l0) LBF(1,h1,l1) LBF(2,h2,l2) LBF(3,h3,l3)
    #pragma unroll 1
    for (int t = 0; t < NSTEP; t += 4) {
        step(t + 0, h0, l0); if (t + 4 < NSTEP) { LBF(t + 4, h0, l0) }
        step(t + 1, h1, l1); if (t + 5 < NSTEP) { LBF(t + 5, h1, l1) }
        step(t + 2, h2, l2); if (t + 6 < NSTEP) { LBF(t + 6, h2, l2) }
        step(t + 3, h3, l3); if (t + 7 < NSTEP) { LBF(t + 7, h3, l3) }
    }
    #undef LBF

    // ---------- Stage 3 ----------
    __syncthreads();   // all A-tile reads done before aliasing writes
    // D layout: col = lane&15, row = (lane>>4)*4 + reg (m89-verified)
    #pragma unroll
    for (int r = 0; r < 4; ++r)
        simsL[(lg*4 + r) * K_N + w*16 + lr] = acc[r];
    __syncthreads();

    {
        // wave w owns row w
        float4 c = *reinterpret_cast<const float4*>(&simsL[w * K_N + lane * 4]);
        int row = brow + w;
        *reinterpret_cast<float4*>(&o_sims[(size_t)row * K_N + lane * 4]) = c;
        float v1b = c.x; int i1 = lane * 4;
        float v2b = -INFINITY; int i2 = 0;
        {
            float vals[3] = {c.y, c.z, c.w};
            #pragma unroll
            for (int j = 0; j < 3; ++j) {
                float val = vals[j]; int idx = lane * 4 + j + 1;
                if (val > v1b) { v2b = v1b; i2 = i1; v1b = val; i1 = idx; }
                else if (val > v2b) { v2b = val; i2 = idx; }
            }
        }
        #pragma unroll
        for (int o = 1; o < 64; o <<= 1) {
            float ov1 = __shfl_xor(v1b, o);
            float ov2 = __shfl_xor(v2b, o);
            int   oi1 = __shfl_xor(i1, o);
            int   oi2 = __shfl_xor(i2, o);
            if (ov1 > v1b || (ov1 == v1b && oi1 < i1)) {
                float nv2; int ni2;
                if (v1b > ov2 || (v1b == ov2 && i1 < oi2)) { nv2 = v1b; ni2 = i1; }
                else { nv2 = ov2; ni2 = oi2; }
                v1b = ov1; i1 = oi1; v2b = nv2; i2 = ni2;
            } else if (ov1 > v2b || (ov1 == v2b && oi1 < i2)) {
                v2b = ov1; i2 = oi1;
            }
        }
        const float4* cent4 = reinterpret_cast<const float4*>(cent);
        #pragma unroll
        for (int q = 0; q < 4; ++q) {
            float4 g1 = cent4[(size_t)i1 * 256 + q * 64 + lane];
            float4 g2 = cent4[(size_t)i2 * 256 + q * 64 + lane];
            reinterpret_cast<float4*>(o_dpcent + (size_t)row * D_N)[q*64 + lane] = g1;
            reinterpret_cast<float4*>(o_hneg   + (size_t)row * D_N)[q*64 + lane] = g2;
        }
        if (lane == 0) {
            o_dpidx[row] = (float)i1;
            o_hnidx[row] = (float)i2;
            o_top1[row]  = v2b;
            widx[row]    = i1;
        }
    }
    __threadfence();
    cg::this_grid().sync();

    // ---------- Phase C: dp_cluster + index_dp, 17 rows per block ----------
    {
        const int4* w4 = reinterpret_cast<const int4*>(widx);
        int4 ix = w4[tid];                       // hoisted: same every row
        int j = tid * 4;
        #pragma unroll 1
        for (int rr = 0; rr < 17; ++rr) {
            int gr = bid * 17 + rr;
            if (gr < B_N) {
                int me = widx[gr];
                float4 v;
                v.x = (ix.x == me && (j + 0) != gr) ? 1.0f : 0.0f;
                v.y = (ix.y == me && (j + 1) != gr) ? 1.0f : 0.0f;
                v.z = (ix.z == me && (j + 2) != gr) ? 1.0f : 0.0f;
                v.w = (ix.w == me && (j + 3) != gr) ? 1.0f : 0.0f;
                *reinterpret_cast<float4*>(o_clust + (size_t)gr * B_N + j) = v;
            } else {
                int k = gr - B_N;
                float4 v;
                v.x = (ix.x == k) ? 1.0f : 0.0f;
                v.y = (ix.y == k) ? 1.0f : 0.0f;
                v.z = (ix.z == k) ? 1.0f : 0.0f;
                v.w = (ix.w == k) ? 1.0f : 0.0f;
                *reinterpret_cast<float4*>(o_idxdp + (size_t)k * B_N + j) = v;
            }
        }
    }
}

extern "C" void kernel_launch(void* const* d_in, const int* in_sizes, int n_in,
                              void* d_out, int out_size, void* d_ws, size_t ws_size,
                              hipStream_t stream)
{
    const float* dp   = (const float*)d_in[0];   // 4096 x 1024 f32
    const float* cent = (const float*)d_in[1];   // 256 x 1024 f32
    // d_in[2] (batch_cos_sim) is unused by the reference outputs.
    float* out = (float*)d_out;

    float* o_sims   = out;                 // 4096*256
    float* o_dpidx  = out + 1048576;       // 4096
    float* o_clust  = out + 1052672;       // 4096*4096
    float* o_idxdp  = out + 17829888;      // 256*4096
    float* o_dpcent = out + 18878464;      // 4096*1024
    float* o_hneg   = out + 23072768;      // 4096*1024
    float* o_hnidx  = out + 27267072;      // 4096
    float* o_top1   = out + 27271168;      // 4096

    char* ws = (char*)d_ws;
    ushort* phi  = (ushort*)ws;                         // 512 KiB packed hi
    ushort* plo  = (ushort*)(ws + (512u << 10));        // 512 KiB packed lo
    int*    widx = (int*)(ws + (1u << 20));             // 16 KiB

    void* args[] = {
        (void*)&dp, (void*)&cent, (void*)&phi, (void*)&plo, (void*)&widx,
        (void*)&o_sims, (void*)&o_dpidx, (void*)&o_clust, (void*)&o_idxdp,
        (void*)&o_dpcent, (void*)&o_hneg, (void*)&o_hnidx, (void*)&o_top1
    };
    hipLaunchCooperativeKernel((void*)kfused_kernel, dim3(K_N), dim3(1024),
                               args, 0, stream);
}

// Round 15
// 44.062 us; speedup vs baseline: 6.3758x; 6.3758x over previous
//
#include <hip/hip_runtime.h>
#include <hip/hip_bf16.h>
#include <math.h>

#define B_N 4096
#define D_N 1024
#define K_N 256
#define NSTEP 32

typedef __attribute__((ext_vector_type(8))) short bf16x8;           // 4 VGPR
typedef __attribute__((ext_vector_type(8))) unsigned short u16x8;   // 4 VGPR
typedef __attribute__((ext_vector_type(4))) float f32x4;            // MFMA C/D

static constexpr float K_EPS = 1e-8f;

static __device__ __forceinline__ unsigned short f32_to_bf16_rne(float f) {
    unsigned x = __builtin_bit_cast(unsigned, f);
    unsigned r = (x + 0x7FFFu + ((x >> 16) & 1u)) >> 16;
    return (unsigned short)r;
}
static __device__ __forceinline__ float bf16_bits_to_f32(unsigned short h) {
    unsigned x = ((unsigned)h) << 16;
    return __builtin_bit_cast(float, x);
}
static __device__ __forceinline__ void cvt8(
    float e0, float e1, float e2, float e3,
    float e4, float e5, float e6, float e7, u16x8& hv, u16x8& lv)
{
    ushort h0=f32_to_bf16_rne(e0), h1=f32_to_bf16_rne(e1),
           h2=f32_to_bf16_rne(e2), h3=f32_to_bf16_rne(e3),
           h4=f32_to_bf16_rne(e4), h5=f32_to_bf16_rne(e5),
           h6=f32_to_bf16_rne(e6), h7=f32_to_bf16_rne(e7);
    hv = (u16x8){h0,h1,h2,h3,h4,h5,h6,h7};
    lv = (u16x8){f32_to_bf16_rne(e0 - bf16_bits_to_f32(h0)),
                 f32_to_bf16_rne(e1 - bf16_bits_to_f32(h1)),
                 f32_to_bf16_rne(e2 - bf16_bits_to_f32(h2)),
                 f32_to_bf16_rne(e3 - bf16_bits_to_f32(h3)),
                 f32_to_bf16_rne(e4 - bf16_bits_to_f32(h4)),
                 f32_to_bf16_rne(e5 - bf16_bits_to_f32(h5)),
                 f32_to_bf16_rne(e6 - bf16_bits_to_f32(h6)),
                 f32_to_bf16_rne(e7 - bf16_bits_to_f32(h7))};
}

// ---------------------------------------------------------------------------
// Kernel 1: centroid normalize + bf16 hi/lo split into PACKED MFMA-fragment
// layout (R12-verified): chunk[(nt*32+t)*64 + lg*16+lr] = cn[nt*16+lr][t*32+lg*8..+8]
// ---------------------------------------------------------------------------
__global__ __launch_bounds__(256) void kcent_kernel(
    const float* __restrict__ cent,
    ushort* __restrict__ phi, ushort* __restrict__ plo)
{
    int n   = blockIdx.x;
    int tid = threadIdx.x;
    float4 v = reinterpret_cast<const float4*>(cent + (size_t)n * D_N)[tid];
    float s = v.x * v.x + v.y * v.y + v.z * v.z + v.w * v.w;
    #pragma unroll
    for (int o = 32; o > 0; o >>= 1) s += __shfl_down(s, o);
    __shared__ float red[4];
    __shared__ float s_inv;
    if ((tid & 63) == 0) red[tid >> 6] = s;
    __syncthreads();
    if (tid == 0) {
        float t = red[0] + red[1] + red[2] + red[3];
        s_inv = 1.0f / fmaxf(sqrtf(t), K_EPS);
    }
    __syncthreads();
    float inv = s_inv;
    float e[4] = {v.x * inv, v.y * inv, v.z * inv, v.w * inv};
    ushort h4[4], l4[4];
    #pragma unroll
    for (int j = 0; j < 4; ++j) {
        ushort h = f32_to_bf16_rne(e[j]);
        float lo = e[j] - bf16_bits_to_f32(h);
        h4[j] = h;
        l4[j] = f32_to_bf16_rne(lo);
    }
    int nt = n >> 4, lr = n & 15;
    int k8 = tid >> 1, half = tid & 1;
    int t  = k8 >> 2, lg = k8 & 3;
    size_t chunk = (size_t)(nt * 32 + t) * 64 + lg * 16 + lr;
    *reinterpret_cast<ushort4*>(phi + chunk * 8 + half * 4) =
        make_ushort4(h4[0], h4[1], h4[2], h4[3]);
    *reinterpret_cast<ushort4*>(plo + chunk * 8 + half * 4) =
        make_ushort4(l4[0], l4[1], l4[2], l4[3]);
}

// ---------------------------------------------------------------------------
// Kernel 2 (main): fused dp-normalize + split-MFMA GEMM + top-2 + gathers.
// R14: 256 blocks x 1024 threads (16 waves, 4/SIMD — 2x R12's TLP).
//  prologue: depth-8 B prefetch ISSUED BEFORE stage 1 (hides under dp read).
//  Stage 1 : wave w normalizes dp row brow+w (6 shfl_xor), writes swizzled
//            bf16 hi/lo A-tile rows in LDS (R13-verified).
//  Stage 2 : per-wave n-tile w; contiguous 1KB packed-B loads, depth-8
//            rotation (slack ~560cyc >> L2 ~200cyc), 3 MFMA/step, no barriers.
//  Stage 3 : simsL -> wave-w top-2 butterfly -> sims/idx/top1 + cent gathers.
// LDS 80KB, 1 block/CU; launch_bounds(1024) caps VGPR at 128 (est ~100).
// ---------------------------------------------------------------------------
__global__ __launch_bounds__(1024) void kmain_kernel(
    const float* __restrict__ dp, const float* __restrict__ cent,
    const ushort* __restrict__ phi, const ushort* __restrict__ plo,
    float* __restrict__ out_sims, float* __restrict__ out_dpidx,
    float* __restrict__ out_hnidx, float* __restrict__ out_top1,
    float* __restrict__ out_dpcent, float* __restrict__ out_hneg,
    int* __restrict__ ws_dpidx)
{
    __shared__ ushort AhL[16 * 1024];   // 32 KB (swizzled)
    __shared__ ushort AlL[16 * 1024];   // 32 KB
    __shared__ float  simsL[16 * 256];  // 16 KB
    int tid  = threadIdx.x;
    int lane = tid & 63;
    int w    = tid >> 6;        // wave 0..15
    int lr   = lane & 15;
    int lg   = lane >> 4;
    int brow = blockIdx.x * 16;

    // ---- B prefetch bases (wave w owns n-tile w) ----
    const ushort* bh = phi + (size_t)w * 32 * 512 + (size_t)lane * 8;
    const ushort* bl = plo + (size_t)w * 32 * 512 + (size_t)lane * 8;

    #define LBF(t, H, L)                                                  \
        H = *reinterpret_cast<const bf16x8*>(bh + (size_t)(t) * 512);     \
        L = *reinterpret_cast<const bf16x8*>(bl + (size_t)(t) * 512);

    // prologue issued BEFORE stage 1: latency hides under the dp read
    bf16x8 h0,l0,h1,l1,h2,l2,h3,l3,h4,l4,h5,l5,h6,l6,h7,l7;
    LBF(0,h0,l0) LBF(1,h1,l1) LBF(2,h2,l2) LBF(3,h3,l3)
    LBF(4,h4,l4) LBF(5,h5,l5) LBF(6,h6,l6) LBF(7,h7,l7)

    // ---- Stage 1: wave w normalizes row brow+w ----
    {
        const float4* r4 = reinterpret_cast<const float4*>(
            dp + (size_t)(brow + w) * D_N);
        float4 a0 = r4[lane*4+0], a1 = r4[lane*4+1],
               a2 = r4[lane*4+2], a3 = r4[lane*4+3];
        float s = a0.x*a0.x + a0.y*a0.y + a0.z*a0.z + a0.w*a0.w
                + a1.x*a1.x + a1.y*a1.y + a1.z*a1.z + a1.w*a1.w
                + a2.x*a2.x + a2.y*a2.y + a2.z*a2.z + a2.w*a2.w
                + a3.x*a3.x + a3.y*a3.y + a3.z*a3.z + a3.w*a3.w;
        #pragma unroll
        for (int o = 1; o < 64; o <<= 1) s += __shfl_xor(s, o);
        float inv = 1.0f / fmaxf(sqrtf(s), K_EPS);
        u16x8 hv, lv;
        cvt8(a0.x*inv, a0.y*inv, a0.z*inv, a0.w*inv,
             a1.x*inv, a1.y*inv, a1.z*inv, a1.w*inv, hv, lv);
        int slot = (lane*2 + 0) ^ (w & 7);
        *reinterpret_cast<u16x8*>(&AhL[w*1024 + slot*8]) = hv;
        *reinterpret_cast<u16x8*>(&AlL[w*1024 + slot*8]) = lv;
        cvt8(a2.x*inv, a2.y*inv, a2.z*inv, a2.w*inv,
             a3.x*inv, a3.y*inv, a3.z*inv, a3.w*inv, hv, lv);
        slot = (lane*2 + 1) ^ (w & 7);
        *reinterpret_cast<u16x8*>(&AhL[w*1024 + slot*8]) = hv;
        *reinterpret_cast<u16x8*>(&AlL[w*1024 + slot*8]) = lv;
    }
    __syncthreads();

    // ---- Stage 2: K-loop, depth-8 rotation, no barriers ----
    f32x4 acc = {};
    const char* AhC = (const char*)AhL;
    const char* AlC = (const char*)AlL;
    auto step = [&](int t, bf16x8 hb, bf16x8 lb) {
        unsigned ca = (unsigned)((4*t + lg) ^ (lr & 7));
        unsigned ao = (unsigned)lr * 2048u + ca * 16u;
        bf16x8 ah = *reinterpret_cast<const bf16x8*>(AhC + ao);
        bf16x8 al = *reinterpret_cast<const bf16x8*>(AlC + ao);
        acc = __builtin_amdgcn_mfma_f32_16x16x32_bf16(ah, hb, acc, 0, 0, 0);
        acc = __builtin_amdgcn_mfma_f32_16x16x32_bf16(ah, lb, acc, 0, 0, 0);
        acc = __builtin_amdgcn_mfma_f32_16x16x32_bf16(al, hb, acc, 0, 0, 0);
    };
    #pragma unroll 1
    for (int t = 0; t < NSTEP; t += 8) {
        step(t + 0, h0, l0); if (t +  8 < NSTEP) { LBF(t +  8, h0, l0) }
        step(t + 1, h1, l1); if (t +  9 < NSTEP) { LBF(t +  9, h1, l1) }
        step(t + 2, h2, l2); if (t + 10 < NSTEP) { LBF(t + 10, h2, l2) }
        step(t + 3, h3, l3); if (t + 11 < NSTEP) { LBF(t + 11, h3, l3) }
        step(t + 4, h4, l4); if (t + 12 < NSTEP) { LBF(t + 12, h4, l4) }
        step(t + 5, h5, l5); if (t + 13 < NSTEP) { LBF(t + 13, h5, l5) }
        step(t + 6, h6, l6); if (t + 14 < NSTEP) { LBF(t + 14, h6, l6) }
        step(t + 7, h7, l7); if (t + 15 < NSTEP) { LBF(t + 15, h7, l7) }
    }
    #undef LBF

    // ---- Stage 3: simsL -> top-2 -> outputs + gathers ----
    // D layout: col = lane&15, row = (lane>>4)*4 + reg (m89-verified)
    #pragma unroll
    for (int r = 0; r < 4; ++r)
        simsL[(lg*4 + r) * K_N + w*16 + lr] = acc[r];
    __syncthreads();

    {
        float4 c = *reinterpret_cast<const float4*>(&simsL[w * K_N + lane * 4]);
        int row = brow + w;
        *reinterpret_cast<float4*>(&out_sims[(size_t)row * K_N + lane * 4]) = c;
        float v1b = c.x; int i1 = lane * 4;
        float v2b = -INFINITY; int i2 = 0;
        {
            float vals[3] = {c.y, c.z, c.w};
            #pragma unroll
            for (int j = 0; j < 3; ++j) {
                float val = vals[j]; int idx = lane * 4 + j + 1;
                if (val > v1b) { v2b = v1b; i2 = i1; v1b = val; i1 = idx; }
                else if (val > v2b) { v2b = val; i2 = idx; }
            }
        }
        #pragma unroll
        for (int o = 1; o < 64; o <<= 1) {
            float ov1 = __shfl_xor(v1b, o);
            float ov2 = __shfl_xor(v2b, o);
            int   oi1 = __shfl_xor(i1, o);
            int   oi2 = __shfl_xor(i2, o);
            if (ov1 > v1b || (ov1 == v1b && oi1 < i1)) {
                float nv2; int ni2;
                if (v1b > ov2 || (v1b == ov2 && i1 < oi2)) { nv2 = v1b; ni2 = i1; }
                else { nv2 = ov2; ni2 = oi2; }
                v1b = ov1; i1 = oi1; v2b = nv2; i2 = ni2;
            } else if (ov1 > v2b || (ov1 == v2b && oi1 < i2)) {
                v2b = ov1; i2 = oi1;
            }
        }
        const float4* cent4 = reinterpret_cast<const float4*>(cent);
        #pragma unroll
        for (int q = 0; q < 4; ++q) {
            float4 g1 = cent4[(size_t)i1 * 256 + q * 64 + lane];
            float4 g2 = cent4[(size_t)i2 * 256 + q * 64 + lane];
            reinterpret_cast<float4*>(out_dpcent + (size_t)row * D_N)[q*64 + lane] = g1;
            reinterpret_cast<float4*>(out_hneg   + (size_t)row * D_N)[q*64 + lane] = g2;
        }
        if (lane == 0) {
            out_dpidx[row] = (float)i1;
            out_hnidx[row] = (float)i2;
            out_top1[row]  = v2b;
            ws_dpidx[row]  = i1;
        }
    }
}

// ---------------------------------------------------------------------------
// Kernel 3: dp_cluster (B x B) + index_dp (K x B). grid = B_N + K_N blocks;
// fully coalesced float4 stores (1 KB/wave-instr).
// ---------------------------------------------------------------------------
__global__ __launch_bounds__(256) void kclust_kernel(
    const int* __restrict__ dpidx,
    float* __restrict__ out_cluster, float* __restrict__ out_indexdp)
{
    int bid = blockIdx.x;
    int tid = threadIdx.x;
    const int4* dpi4 = reinterpret_cast<const int4*>(dpidx);
    if (bid < B_N) {
        int i = bid;
        int me = dpidx[i];
        float* dst = out_cluster + (size_t)i * B_N;
        #pragma unroll
        for (int q = 0; q < 4; ++q) {
            int j = q * 1024 + tid * 4;
            int4 ix = dpi4[j >> 2];
            float4 v;
            v.x = (ix.x == me && (j + 0) != i) ? 1.0f : 0.0f;
            v.y = (ix.y == me && (j + 1) != i) ? 1.0f : 0.0f;
            v.z = (ix.z == me && (j + 2) != i) ? 1.0f : 0.0f;
            v.w = (ix.w == me && (j + 3) != i) ? 1.0f : 0.0f;
            *reinterpret_cast<float4*>(dst + j) = v;
        }
    } else {
        int k = bid - B_N;
        float* dst = out_indexdp + (size_t)k * B_N;
        #pragma unroll
        for (int q = 0; q < 4; ++q) {
            int j = q * 1024 + tid * 4;
            int4 ix = dpi4[j >> 2];
            float4 v;
            v.x = (ix.x == k) ? 1.0f : 0.0f;
            v.y = (ix.y == k) ? 1.0f : 0.0f;
            v.z = (ix.z == k) ? 1.0f : 0.0f;
            v.w = (ix.w == k) ? 1.0f : 0.0f;
            *reinterpret_cast<float4*>(dst + j) = v;
        }
    }
}

extern "C" void kernel_launch(void* const* d_in, const int* in_sizes, int n_in,
                              void* d_out, int out_size, void* d_ws, size_t ws_size,
                              hipStream_t stream)
{
    const float* dp   = (const float*)d_in[0];   // 4096 x 1024 f32
    const float* cent = (const float*)d_in[1];   // 256 x 1024 f32
    // d_in[2] (batch_cos_sim) is unused by the reference outputs.
    float* out = (float*)d_out;

    float* o_sims   = out;                 // 4096*256
    float* o_dpidx  = out + 1048576;       // 4096
    float* o_clust  = out + 1052672;       // 4096*4096
    float* o_idxdp  = out + 17829888;      // 256*4096
    float* o_dpcent = out + 18878464;      // 4096*1024
    float* o_hneg   = out + 23072768;      // 4096*1024
    float* o_hnidx  = out + 27267072;      // 4096
    float* o_top1   = out + 27271168;      // 4096

    char* ws = (char*)d_ws;
    ushort* phi  = (ushort*)ws;                         // 512 KiB packed hi
    ushort* plo  = (ushort*)(ws + (512u << 10));        // 512 KiB packed lo
    int*    widx = (int*)(ws + (1u << 20));             // 16 KiB

    hipLaunchKernelGGL(kcent_kernel, dim3(K_N), dim3(256), 0, stream,
                       cent, phi, plo);
    hipLaunchKernelGGL(kmain_kernel, dim3(B_N / 16), dim3(1024), 0, stream,
                       dp, cent, phi, plo,
                       o_sims, o_dpidx, o_hnidx, o_top1,
                       o_dpcent, o_hneg, widx);
    hipLaunchKernelGGL(kclust_kernel, dim3(B_N + K_N), dim3(256), 0, stream,
                       widx, o_clust, o_idxdp);
}